// Round 12
// baseline (370.006 us; speedup 1.0000x reference)
//
#include <hip/hip_runtime.h>

typedef __attribute__((ext_vector_type(8))) short short8;
typedef __attribute__((ext_vector_type(4))) float f32x4;
typedef unsigned short ushort_t;

#define BAR()   __builtin_amdgcn_s_barrier()
#define LGKM0() asm volatile("s_waitcnt lgkmcnt(0)" ::: "memory")
#define VM0()   asm volatile("s_waitcnt vmcnt(0)" ::: "memory")
#define PRIO(n) __builtin_amdgcn_s_setprio(n)
#define MFMA(a_, b_, c_) __builtin_amdgcn_mfma_f32_16x16x32_bf16(a_, b_, c_, 0, 0, 0)

// ---------- helpers ----------
__device__ __forceinline__ unsigned short f2bf(float f) {
  unsigned u = __builtin_bit_cast(unsigned, f);
  u += 0x7FFFu + ((u >> 16) & 1u);   // round-to-nearest-even
  return (unsigned short)(u >> 16);
}

__device__ __forceinline__ void gl_lds16(const void* g, void* l) {
  __builtin_amdgcn_global_load_lds(
      (const __attribute__((address_space(1))) void*)g,
      (__attribute__((address_space(3))) void*)l, 16, 0, 0);
}

// ---------- kernel 1: x (f32) -> bf16 ----------
__global__ __launch_bounds__(256) void cvt_x(const float* __restrict__ x,
                                             ushort_t* __restrict__ xb) {
  size_t i = ((size_t)blockIdx.x * 256 + threadIdx.x) * 8;
  float4 v0 = *(const float4*)(x + i);
  float4 v1 = *(const float4*)(x + i + 4);
  union { ushort_t s[8]; uint4 v; } o;
  o.s[0] = f2bf(v0.x); o.s[1] = f2bf(v0.y); o.s[2] = f2bf(v0.z); o.s[3] = f2bf(v0.w);
  o.s[4] = f2bf(v1.x); o.s[5] = f2bf(v1.y); o.s[6] = f2bf(v1.z); o.s[7] = f2bf(v1.w);
  *(uint4*)(xb + i) = o.v;
}

// ---------- kernel 2: W_eff = W + A@B, stored bf16 (8 elems/thread) ----------
__global__ __launch_bounds__(256) void build_weff(const float* __restrict__ W,
                                                  const float* __restrict__ A,
                                                  const float* __restrict__ B,
                                                  ushort_t* __restrict__ Weff) {
  const int K = 4096, R = 16;
  const int n = blockIdx.y;
  const int k = (blockIdx.x * 256 + threadIdx.x) * 8;
  float4 w0 = *(const float4*)(W + (size_t)n * K + k);
  float4 w1 = *(const float4*)(W + (size_t)n * K + k + 4);
  float s0 = w0.x, s1 = w0.y, s2 = w0.z, s3 = w0.w;
  float s4 = w1.x, s5 = w1.y, s6 = w1.z, s7 = w1.w;
#pragma unroll
  for (int r = 0; r < R; ++r) {
    float a = A[n * R + r];
    float4 b0 = *(const float4*)(B + (size_t)r * K + k);
    float4 b1 = *(const float4*)(B + (size_t)r * K + k + 4);
    s0 += a * b0.x; s1 += a * b0.y; s2 += a * b0.z; s3 += a * b0.w;
    s4 += a * b1.x; s5 += a * b1.y; s6 += a * b1.z; s7 += a * b1.w;
  }
  union { ushort_t s[8]; uint4 v; } o;
  o.s[0] = f2bf(s0); o.s[1] = f2bf(s1); o.s[2] = f2bf(s2); o.s[3] = f2bf(s3);
  o.s[4] = f2bf(s4); o.s[5] = f2bf(s5); o.s[6] = f2bf(s6); o.s[7] = f2bf(s7);
  *(uint4*)(Weff + (size_t)n * K + k) = o.v;
}

// ---------- kernel 3: 256x256 bf16 GEMM, BK=32, 64 KiB LDS -> 2 blocks/CU ----------
// Round-4 champion's rhythm (250 us, conflicts 0) with HALVED LDS footprint:
// [2 dbuf][A,B][256 rows][32 cols] bf16 = 64 KiB -> exactly 2 co-resident
// blocks/CU (512 blocks/256 CU). Mechanism targeted: at 1 block/CU (round 4,
// 128 KiB) all 8 waves share barriers -> LDS(2304cy) and MFMA(2483cy) bursts
// alternate, never overlap (wall 4700 cy/64K). Two INDEPENDENT blocks desync
// -> block A's MFMA phase fills block B's read phase (m114/m97 mechanism).
// Per 64 K of work, everything else is round-4-identical: 8 barriers, 24
// ds_read_b128/wave, 8 gl_lds issues/thread, 64 MFMA/wave, same swizzle
// (byte^=((row>>3)&1)<<5, pre-swizzled source + XOR'd read, rule 21), same
// 2Mx4N wave layout, same epilogue.
// Per K-step (BK=32), strict dbuf, prefetch distance 1:
//   P1: rd a0-3 + b0-3 (cur); stage A,B(t+1)->cur^1; BAR; lgkm0; QUAD(0); BAR
//   P2: rd a4-7 (cur);        BAR; lgkm0; QUAD(4); VM0; BAR
// VM0 drains t+1's 4 issues ~1800 cy after issue (>900 cy HBM) -> cheap.

__device__ __forceinline__ void stage_half(const ushort_t* __restrict__ G, int row0, int kc,
                                           ushort_t* half, int tid) {
#pragma unroll
  for (int r = 0; r < 2; ++r) {
    const int idx  = r * 512 + tid;
    const int lrow = idx >> 2;                                  // 0..255
    const int cb   = ((idx & 3) * 16) ^ (((lrow >> 3) & 1) << 5); // pre-swizzled source col (bytes)
    const ushort_t* src = G + (size_t)(row0 + lrow) * 4096 + kc + (cb >> 1);
    char* dst = (char*)half + (size_t)(r * 512 + (tid & ~63)) * 16; // wave-uniform; HW adds lane*16
    gl_lds16(src, dst);
  }
}

__global__ __launch_bounds__(512) void gemm256(const ushort_t* __restrict__ Xb,
                                               const ushort_t* __restrict__ Wb,
                                               float* __restrict__ C) {
  const int N = 4096;
  const int NT = 4096 / 32;                 // 128 K-steps of 32
  __shared__ __align__(16) ushort_t lds[2][2][256 * 32];  // [buf][A,B][row][col] = 64 KiB

  const int tid = threadIdx.x;
  const int l   = tid & 63;
  const int w   = tid >> 6;
  const int wm  = w >> 2;                   // 0..1
  const int wn  = w & 3;                    // 0..3

  // T1: bijective XCD chunking — 512 blocks = 8 chunks of 8x8 tiles (grid 32x16)
  const int bid = blockIdx.x;
  const int c = bid & 7, q = bid >> 3;
  const int tm = (c >> 1) * 8 + (q >> 3);   // 0..31
  const int tn = (c & 1) * 8 + (q & 7);     // 0..15
  const int bm = tm * 256, bn = tn * 256;

  // fragment LDS byte offsets within a half (swizzled read side)
  const int colb = ((l >> 4) * 16) ^ (((l >> 3) & 1) << 5);
  int aoff[8], boff[4];
#pragma unroll
  for (int mi = 0; mi < 8; ++mi) aoff[mi] = (wm * 128 + mi * 16 + (l & 15)) * 64 + colb;
#pragma unroll
  for (int ni = 0; ni < 4; ++ni) boff[ni] = (wn * 64 + ni * 16 + (l & 15)) * 64 + colb;

  f32x4 acc[8][4];
#pragma unroll
  for (int i = 0; i < 8; ++i)
#pragma unroll
    for (int j = 0; j < 4; ++j) acc[i][j] = (f32x4)(0.0f);

  // prologue: stage step 0 into buf 0, drain, barrier
  stage_half(Xb, bm, 0, lds[0][0], tid);
  stage_half(Wb, bn, 0, lds[0][1], tid);
  VM0();
  BAR();

  short8 af0, af1, af2, af3, bf0, bf1, bf2, bf3;

#define LDA(P_, I0_) do { \
    af0 = *(const short8*)((const char*)(P_) + aoff[(I0_) + 0]); \
    af1 = *(const short8*)((const char*)(P_) + aoff[(I0_) + 1]); \
    af2 = *(const short8*)((const char*)(P_) + aoff[(I0_) + 2]); \
    af3 = *(const short8*)((const char*)(P_) + aoff[(I0_) + 3]); \
  } while (0)
#define LDB(P_) do { \
    bf0 = *(const short8*)((const char*)(P_) + boff[0]); \
    bf1 = *(const short8*)((const char*)(P_) + boff[1]); \
    bf2 = *(const short8*)((const char*)(P_) + boff[2]); \
    bf3 = *(const short8*)((const char*)(P_) + boff[3]); \
  } while (0)
#define QUAD(M0_) do { \
    acc[(M0_)+0][0] = MFMA(af0, bf0, acc[(M0_)+0][0]); \
    acc[(M0_)+0][1] = MFMA(af0, bf1, acc[(M0_)+0][1]); \
    acc[(M0_)+0][2] = MFMA(af0, bf2, acc[(M0_)+0][2]); \
    acc[(M0_)+0][3] = MFMA(af0, bf3, acc[(M0_)+0][3]); \
    acc[(M0_)+1][0] = MFMA(af1, bf0, acc[(M0_)+1][0]); \
    acc[(M0_)+1][1] = MFMA(af1, bf1, acc[(M0_)+1][1]); \
    acc[(M0_)+1][2] = MFMA(af1, bf2, acc[(M0_)+1][2]); \
    acc[(M0_)+1][3] = MFMA(af1, bf3, acc[(M0_)+1][3]); \
    acc[(M0_)+2][0] = MFMA(af2, bf0, acc[(M0_)+2][0]); \
    acc[(M0_)+2][1] = MFMA(af2, bf1, acc[(M0_)+2][1]); \
    acc[(M0_)+2][2] = MFMA(af2, bf2, acc[(M0_)+2][2]); \
    acc[(M0_)+2][3] = MFMA(af2, bf3, acc[(M0_)+2][3]); \
    acc[(M0_)+3][0] = MFMA(af3, bf0, acc[(M0_)+3][0]); \
    acc[(M0_)+3][1] = MFMA(af3, bf1, acc[(M0_)+3][1]); \
    acc[(M0_)+3][2] = MFMA(af3, bf2, acc[(M0_)+3][2]); \
    acc[(M0_)+3][3] = MFMA(af3, bf3, acc[(M0_)+3][3]); \
  } while (0)

  int cur = 0;
  for (int t = 0; t < NT; ++t) {
    const ushort_t* Ah = lds[cur][0];
    const ushort_t* Bh = lds[cur][1];

    // P1: read a0-3 + b, stage step t+1 into cur^1
    LDA(Ah, 0); LDB(Bh);
    if (t + 1 < NT) {
      const int kc = (t + 1) * 32;
      stage_half(Xb, bm, kc, lds[cur ^ 1][0], tid);
      stage_half(Wb, bn, kc, lds[cur ^ 1][1], tid);
    }
    BAR(); LGKM0(); PRIO(1);
    QUAD(0);
    PRIO(0); BAR();

    // P2: read a4-7
    LDA(Ah, 4);
    BAR(); LGKM0(); PRIO(1);
    QUAD(4);
    PRIO(0);
    VM0();          // t+1's 4 issues landed (~1800 cy since issue)
    BAR();          // all waves done with cur; cur^1 ready
    cur ^= 1;
  }

  // epilogue: C/D layout col = lane&15, row = (lane>>4)*4 + j
  const int erow = bm + wm * 128 + (l >> 4) * 4;
  const int ecol = bn + wn * 64 + (l & 15);
#pragma unroll
  for (int mi = 0; mi < 8; ++mi) {
#pragma unroll
    for (int ni = 0; ni < 4; ++ni) {
      float* cp = C + (size_t)(erow + mi * 16) * N + ecol + ni * 16;
#pragma unroll
      for (int j = 0; j < 4; ++j) cp[(size_t)j * N] = acc[mi][ni][j];
    }
  }
}

extern "C" void kernel_launch(void* const* d_in, const int* in_sizes, int n_in,
                              void* d_out, int out_size, void* d_ws, size_t ws_size,
                              hipStream_t stream) {
  const float* x = (const float*)d_in[0];   // [8192, 4096]
  const float* W = (const float*)d_in[1];   // [4096, 4096]
  const float* A = (const float*)d_in[2];   // [4096, 16]
  const float* B = (const float*)d_in[3];   // [16, 4096]
  float* out = (float*)d_out;               // [8192, 4096]

  ushort_t* xb = (ushort_t*)d_ws;                                    // 64 MB
  ushort_t* wb = (ushort_t*)((char*)d_ws + (size_t)8192 * 4096 * 2); // 32 MB

  cvt_x<<<16384, 256, 0, stream>>>(x, xb);
  dim3 gw(2, 4096);
  build_weff<<<gw, 256, 0, stream>>>(W, A, B, wb);
  gemm256<<<512, 512, 0, stream>>>(xb, wb, out);  // grid 32x16 tiles, XCD-chunked
}

// Round 14
// 354.170 us; speedup vs baseline: 1.0447x; 1.0447x over previous
//
#include <hip/hip_runtime.h>

typedef __attribute__((ext_vector_type(8))) short short8;
typedef __attribute__((ext_vector_type(4))) float f32x4;
typedef unsigned short ushort_t;

#define BAR()   __builtin_amdgcn_s_barrier()
#define LGKM0() asm volatile("s_waitcnt lgkmcnt(0)" ::: "memory")
#define VM6()   asm volatile("s_waitcnt vmcnt(6)" ::: "memory")
#define VM0()   asm volatile("s_waitcnt vmcnt(0)" ::: "memory")
#define PRIO(n) __builtin_amdgcn_s_setprio(n)
#define MFMA(a_, b_, c_) __builtin_amdgcn_mfma_f32_16x16x32_bf16(a_, b_, c_, 0, 0, 0)

// ---------- helpers ----------
__device__ __forceinline__ unsigned short f2bf(float f) {
  unsigned u = __builtin_bit_cast(unsigned, f);
  u += 0x7FFFu + ((u >> 16) & 1u);   // round-to-nearest-even
  return (unsigned short)(u >> 16);
}

__device__ __forceinline__ void gl_lds16(const void* g, void* l) {
  __builtin_amdgcn_global_load_lds(
      (const __attribute__((address_space(1))) void*)g,
      (__attribute__((address_space(3))) void*)l, 16, 0, 0);
}

// ---------- kernel 1: x (f32) -> bf16 ----------
__global__ __launch_bounds__(256) void cvt_x(const float* __restrict__ x,
                                             ushort_t* __restrict__ xb) {
  size_t i = ((size_t)blockIdx.x * 256 + threadIdx.x) * 8;
  float4 v0 = *(const float4*)(x + i);
  float4 v1 = *(const float4*)(x + i + 4);
  union { ushort_t s[8]; uint4 v; } o;
  o.s[0] = f2bf(v0.x); o.s[1] = f2bf(v0.y); o.s[2] = f2bf(v0.z); o.s[3] = f2bf(v0.w);
  o.s[4] = f2bf(v1.x); o.s[5] = f2bf(v1.y); o.s[6] = f2bf(v1.z); o.s[7] = f2bf(v1.w);
  *(uint4*)(xb + i) = o.v;
}

// ---------- kernel 2: W_eff = W + A@B, stored bf16 (8 elems/thread) ----------
__global__ __launch_bounds__(256) void build_weff(const float* __restrict__ W,
                                                  const float* __restrict__ A,
                                                  const float* __restrict__ B,
                                                  ushort_t* __restrict__ Weff) {
  const int K = 4096, R = 16;
  const int n = blockIdx.y;
  const int k = (blockIdx.x * 256 + threadIdx.x) * 8;
  float4 w0 = *(const float4*)(W + (size_t)n * K + k);
  float4 w1 = *(const float4*)(W + (size_t)n * K + k + 4);
  float s0 = w0.x, s1 = w0.y, s2 = w0.z, s3 = w0.w;
  float s4 = w1.x, s5 = w1.y, s6 = w1.z, s7 = w1.w;
#pragma unroll
  for (int r = 0; r < R; ++r) {
    float a = A[n * R + r];                       // uniform per block -> scalar load
    float4 b0 = *(const float4*)(B + (size_t)r * K + k);
    float4 b1 = *(const float4*)(B + (size_t)r * K + k + 4);
    s0 += a * b0.x; s1 += a * b0.y; s2 += a * b0.z; s3 += a * b0.w;
    s4 += a * b1.x; s5 += a * b1.y; s6 += a * b1.z; s7 += a * b1.w;
  }
  union { ushort_t s[8]; uint4 v; } o;
  o.s[0] = f2bf(s0); o.s[1] = f2bf(s1); o.s[2] = f2bf(s2); o.s[3] = f2bf(s3);
  o.s[4] = f2bf(s4); o.s[5] = f2bf(s5); o.s[6] = f2bf(s6); o.s[7] = f2bf(s7);
  *(uint4*)(Weff + (size_t)n * K + k) = o.v;      // 16 B/lane store
}

// ---------- kernel 3: 256x256 8-phase bf16 GEMM (session champion) ----------
// Measured (rounds 4 & 11): 247-250 us, MfmaUtil 51.5%, SQ_LDS_BANK_CONFLICT 0.
// = 1113 TF, 45% of dense bf16 MFMA peak. Structural constraint documented in
// session notes: per 64-K-slice, MFMA (~2483 cy) and ds_read (~2304 cy) pipes
// serialize under 8-wave barrier lockstep; all plain-HIP attempts to overlap
// them (free-run, m201 geometry x2, 32x32 MFMA, 4-wave ILP, 2-block TLP)
// measured neutral-to-worse (rounds 5-10, 12).
// C[M][N] = Xb[M][K] * Wb[N][K]^T. BM=BN=256, BK=64 (2 k-halves of 32).
// LDS: 2 dbuf x 4 halves (A-k0, A-k1, B-k0, B-k1) x [256 rows][32 cols] = 128 KiB.
// 8 waves (2M x 4N); per-wave C = 128x64 = acc[8][4] f32x4.
// Per K-tile 4 phases: P1{rd a0-3/k0 + b0-3/k0, stage A-k1(t+1)->buf^1}  Q(m0-3,k0)
//                      P2{rd a4-7/k0,            stage B-k0(t+2)->buf}    Q(m4-7,k0)
//                      P3{rd a0-3/k1 + b0-3/k1,  stage A-k0(t+2)->buf}    Q(m0-3,k1)
//                      P4{rd a4-7/k1,            stage B-k1(t+2)->buf, vmcnt(6)} Q(m4-7,k1)
// vmcnt(6) = 3 half-tiles (2 loads each) in flight; tile t+1 fully landed at its BAR.
// st_16x32 swizzle: byte^=((row>>3)&1)<<5, pre-swizzled global SOURCE at stage +
// same XOR on ds_read addr; LDS dest linear for global_load_lds (rule 21).

__device__ __forceinline__ void stage_half(const ushort_t* __restrict__ G, int row0, int kc,
                                           ushort_t* half, int tid) {
#pragma unroll
  for (int r = 0; r < 2; ++r) {
    const int idx  = r * 512 + tid;
    const int lrow = idx >> 2;                                  // 0..255
    const int cb   = ((idx & 3) * 16) ^ (((lrow >> 3) & 1) << 5); // pre-swizzled source col (bytes)
    const ushort_t* src = G + (size_t)(row0 + lrow) * 4096 + kc + (cb >> 1);
    char* dst = (char*)half + (size_t)(r * 512 + (tid & ~63)) * 16; // wave-uniform; HW adds lane*16
    gl_lds16(src, dst);
  }
}

__global__ __launch_bounds__(512, 2) void gemm256(const ushort_t* __restrict__ Xb,
                                                  const ushort_t* __restrict__ Wb,
                                                  float* __restrict__ C) {
  const int N = 4096;
  const int NT = 4096 / 64;                 // 64 K-tiles
  __shared__ __align__(16) ushort_t lds[2][4][256 * 32];  // [buf][A0,A1,B0,B1][row][col]

  const int tid = threadIdx.x;
  const int l   = tid & 63;
  const int w   = tid >> 6;
  const int wm  = w >> 2;                   // 0..1
  const int wn  = w & 3;                    // 0..3

  // T1: bijective XCD chunking — 512 blocks = 8 chunks of 8x8 tiles (grid 32x16)
  const int bid = blockIdx.x;
  const int c = bid & 7, q = bid >> 3;
  const int tm = (c >> 1) * 8 + (q >> 3);   // 0..31
  const int tn = (c & 1) * 8 + (q & 7);     // 0..15
  const int bm = tm * 256, bn = tn * 256;

  // fragment LDS byte offsets within a half (swizzled read side)
  const int colb = ((l >> 4) * 16) ^ (((l >> 3) & 1) << 5);
  int aoff[8], boff[4];
#pragma unroll
  for (int mi = 0; mi < 8; ++mi) aoff[mi] = (wm * 128 + mi * 16 + (l & 15)) * 64 + colb;
#pragma unroll
  for (int ni = 0; ni < 4; ++ni) boff[ni] = (wn * 64 + ni * 16 + (l & 15)) * 64 + colb;

  f32x4 acc[8][4];
#pragma unroll
  for (int i = 0; i < 8; ++i)
#pragma unroll
    for (int j = 0; j < 4; ++j) acc[i][j] = (f32x4)(0.0f);

  // prologue: 7 halves (tile0 all + tile1 B-k0,A-k0,B-k1), then vmcnt(6) -> tile0 landed
  stage_half(Wb, bn, 0,  lds[0][2], tid);
  stage_half(Xb, bm, 0,  lds[0][0], tid);
  stage_half(Wb, bn, 32, lds[0][3], tid);
  stage_half(Xb, bm, 32, lds[0][1], tid);
  stage_half(Wb, bn, 64, lds[1][2], tid);
  stage_half(Xb, bm, 64, lds[1][0], tid);
  stage_half(Wb, bn, 96, lds[1][3], tid);
  VM6();
  BAR();

  short8 af0, af1, af2, af3, bf0, bf1, bf2, bf3;

#define LDA(P_, I0_) do { \
    af0 = *(const short8*)((const char*)(P_) + aoff[(I0_) + 0]); \
    af1 = *(const short8*)((const char*)(P_) + aoff[(I0_) + 1]); \
    af2 = *(const short8*)((const char*)(P_) + aoff[(I0_) + 2]); \
    af3 = *(const short8*)((const char*)(P_) + aoff[(I0_) + 3]); \
  } while (0)
#define LDB(P_) do { \
    bf0 = *(const short8*)((const char*)(P_) + boff[0]); \
    bf1 = *(const short8*)((const char*)(P_) + boff[1]); \
    bf2 = *(const short8*)((const char*)(P_) + boff[2]); \
    bf3 = *(const short8*)((const char*)(P_) + boff[3]); \
  } while (0)
#define QUAD(M0_) do { \
    acc[(M0_)+0][0] = MFMA(af0, bf0, acc[(M0_)+0][0]); \
    acc[(M0_)+0][1] = MFMA(af0, bf1, acc[(M0_)+0][1]); \
    acc[(M0_)+0][2] = MFMA(af0, bf2, acc[(M0_)+0][2]); \
    acc[(M0_)+0][3] = MFMA(af0, bf3, acc[(M0_)+0][3]); \
    acc[(M0_)+1][0] = MFMA(af1, bf0, acc[(M0_)+1][0]); \
    acc[(M0_)+1][1] = MFMA(af1, bf1, acc[(M0_)+1][1]); \
    acc[(M0_)+1][2] = MFMA(af1, bf2, acc[(M0_)+1][2]); \
    acc[(M0_)+1][3] = MFMA(af1, bf3, acc[(M0_)+1][3]); \
    acc[(M0_)+2][0] = MFMA(af2, bf0, acc[(M0_)+2][0]); \
    acc[(M0_)+2][1] = MFMA(af2, bf1, acc[(M0_)+2][1]); \
    acc[(M0_)+2][2] = MFMA(af2, bf2, acc[(M0_)+2][2]); \
    acc[(M0_)+2][3] = MFMA(af2, bf3, acc[(M0_)+2][3]); \
    acc[(M0_)+3][0] = MFMA(af3, bf0, acc[(M0_)+3][0]); \
    acc[(M0_)+3][1] = MFMA(af3, bf1, acc[(M0_)+3][1]); \
    acc[(M0_)+3][2] = MFMA(af3, bf2, acc[(M0_)+3][2]); \
    acc[(M0_)+3][3] = MFMA(af3, bf3, acc[(M0_)+3][3]); \
  } while (0)

  int cur = 0;
  for (int t = 0; t < NT; ++t) {
    const ushort_t* A0h = lds[cur][0];
    const ushort_t* A1h = lds[cur][1];
    const ushort_t* B0h = lds[cur][2];
    const ushort_t* B1h = lds[cur][3];
    const int kc2 = (t + 2) * 64;

    // P1
    LDA(A0h, 0); LDB(B0h);
    if (t + 1 < NT) stage_half(Xb, bm, (t + 1) * 64 + 32, lds[cur ^ 1][1], tid);
    BAR(); LGKM0(); PRIO(1);
    QUAD(0);
    PRIO(0); BAR();

    // P2
    LDA(A0h, 4);
    if (t + 2 < NT) stage_half(Wb, bn, kc2, lds[cur][2], tid);
    BAR(); LGKM0(); PRIO(1);
    QUAD(4);
    PRIO(0); BAR();

    // P3
    LDA(A1h, 0); LDB(B1h);
    if (t + 2 < NT) stage_half(Xb, bm, kc2, lds[cur][0], tid);
    BAR(); LGKM0(); PRIO(1);
    QUAD(0);
    PRIO(0); BAR();

    // P4
    LDA(A1h, 4);
    if (t + 2 < NT) stage_half(Wb, bn, kc2 + 32, lds[cur][3], tid);
    if (t + 2 < NT) { VM6(); } else { VM0(); }
    BAR(); LGKM0(); PRIO(1);
    QUAD(4);
    PRIO(0); BAR();

    cur ^= 1;
  }

  // epilogue: C/D layout col = lane&15, row = (lane>>4)*4 + j
  const int erow = bm + wm * 128 + (l >> 4) * 4;
  const int ecol = bn + wn * 64 + (l & 15);
#pragma unroll
  for (int mi = 0; mi < 8; ++mi) {
#pragma unroll
    for (int ni = 0; ni < 4; ++ni) {
      float* cp = C + (size_t)(erow + mi * 16) * N + ecol + ni * 16;
#pragma unroll
      for (int j = 0; j < 4; ++j) cp[(size_t)j * N] = acc[mi][ni][j];
    }
  }
}

extern "C" void kernel_launch(void* const* d_in, const int* in_sizes, int n_in,
                              void* d_out, int out_size, void* d_ws, size_t ws_size,
                              hipStream_t stream) {
  const float* x = (const float*)d_in[0];   // [8192, 4096]
  const float* W = (const float*)d_in[1];   // [4096, 4096]
  const float* A = (const float*)d_in[2];   // [4096, 16]
  const float* B = (const float*)d_in[3];   // [16, 4096]
  float* out = (float*)d_out;               // [8192, 4096]

  ushort_t* xb = (ushort_t*)d_ws;                                    // 64 MB
  ushort_t* wb = (ushort_t*)((char*)d_ws + (size_t)8192 * 4096 * 2); // 32 MB

  cvt_x<<<16384, 256, 0, stream>>>(x, xb);
  dim3 gw(2, 4096);
  build_weff<<<gw, 256, 0, stream>>>(W, A, B, wb);
  gemm256<<<512, 512, 0, stream>>>(xb, wb, out);  // grid 32x16 tiles, XCD-chunked
}